// Round 4
// baseline (374.697 us; speedup 1.0000x reference)
//
#include <hip/hip_runtime.h>

#define Nn 1024

typedef __attribute__((ext_vector_type(8))) short short8v;
typedef __attribute__((ext_vector_type(4))) float floatx4;

__device__ __forceinline__ float fsilu(float v) { return v / (1.0f + __expf(-v)); }
__device__ __forceinline__ float fsig(float v)  { return 1.0f / (1.0f + __expf(-v)); }
__device__ __forceinline__ float ftanh10(float v){ return (1.0f - 2.0f / (__expf(2.0f * v) + 1.0f)) * 10.0f; }

// pack two fp32 -> one u32 of 2 bf16 (round-half-up): 2 adds + 1 v_perm
__device__ __forceinline__ unsigned pkbf(float lo, float hi) {
    unsigned a = __float_as_uint(lo) + 0x8000u;
    unsigned b = __float_as_uint(hi) + 0x8000u;
    return __builtin_amdgcn_perm(b, a, 0x07060302u);  // {b.hi16, a.hi16}
}

// Kernel A: ha = h@Wa^T + eb1 ; hb = h@Wb^T ; hn1 = h@nw1[:, :64]^T + nb1
__global__ __launch_bounds__(256) void precompute_kernel(
    const float* __restrict__ h, const float* __restrict__ ew1,
    const float* __restrict__ eb1, const float* __restrict__ nw1,
    const float* __restrict__ nb1, float* __restrict__ ha,
    float* __restrict__ hb, float* __restrict__ hn1)
{
    int t = blockIdx.x * 256 + threadIdx.x;
    int which = t >> 16;
    int rem = t & 65535;
    int i = rem >> 6, o = rem & 63;
    const float* hrow = h + i * 64;
    const float* wrow;
    float acc;
    if (which == 0)      { wrow = ew1 + o * 130;      acc = eb1[o]; }
    else if (which == 1) { wrow = ew1 + o * 130 + 64; acc = 0.0f;   }
    else                 { wrow = nw1 + o * 128;      acc = nb1[o]; }
    #pragma unroll
    for (int k = 0; k < 64; ++k) acc = fmaf(hrow[k], wrow[k], acc);
    if (which == 0)      ha[rem]  = acc;
    else if (which == 1) hb[rem]  = acc;
    else                 hn1[rem] = acc;
}

// Edge pipeline. 1024 blocks x 256 thr (4 waves). Block owns node i0 = blockIdx.x,
// iterates j in 16 chunks of 64. Per chunk each wave owns 16 rows (wave-private
// Tb/dxs slices -> NO barriers in the chunk loop).
// Both GEMMs computed swapped: D^T = W * T^T, so output col = edge row = lane&15.
__global__ __launch_bounds__(256, 3) void edge_mfma_kernel(
    const float* __restrict__ x, const float* __restrict__ Lp,
    const float* __restrict__ ha, const float* __restrict__ hb,
    const float* __restrict__ ew1, const float* __restrict__ ew2,
    const float* __restrict__ eb2, const float* __restrict__ chw,
    const float* __restrict__ chb, const float* __restrict__ aw,
    const float* __restrict__ ab, const float* __restrict__ cww,
    float* __restrict__ agg, float* __restrict__ delta)
{
    __shared__ __align__(16) char Tb[64 * 128];       // 64 rows x 64 bf16, XOR-swizzled
    __shared__ __align__(16) float xs[Nn * 3];
    __shared__ __align__(16) float dxs[3][64];
    __shared__ __align__(16) float ebs[64];
    __shared__ __align__(16) float aws[64];
    __shared__ __align__(16) float chbs[64];
    __shared__ __align__(16) float cwws[64];
    __shared__ __align__(16) float redagg[4][64];
    __shared__ float sdel[4][3];

    const int tid  = threadIdx.x;
    const int wave = tid >> 6, lane = tid & 63;
    const int lr = lane & 15, g = lane >> 4;
    const int i0 = blockIdx.x;
    const int wv16 = wave * 16;
    const int mrow = wv16 + lr;          // the edge row this lane owns in GEMM output
    const int rsub = lane >> 5;          // build: which of 2 rows
    const int kp   = (lane & 31) * 2;    // build: k-pair base (bf16 elements)
    const int ghi  = g >> 1;
    const int selA = (lr + ((g & 1) << 5)) << 2;   // bpermute byte addr
    const int selB = selA + 64;

    // stage x into LDS (float4), biases into LDS
    {
        const float4* xsrc = (const float4*)x;
        float4* xdst = (float4*)xs;
        xdst[tid] = xsrc[tid];
        xdst[tid + 256] = xsrc[tid + 256];
        xdst[tid + 512] = xsrc[tid + 512];
    }
    if (tid < 64) {
        ebs[tid]  = eb2[tid];
        aws[tid]  = aw[tid];
        chbs[tid] = chb[tid];
        cwws[tid] = cww[tid];
    }

    // weight fragments in registers (bf16), layout: row n = lane&15, k 8-contig per g
    short8v bw2[2][4], bwc[2][4];
    #pragma unroll
    for (int kt = 0; kt < 2; ++kt)
      #pragma unroll
      for (int nt = 0; nt < 4; ++nt) {
        int n = nt * 16 + lr;
        int k0 = kt * 32 + g * 8;
        float4 lo = *(const float4*)(ew2 + n * 64 + k0);
        float4 hi = *(const float4*)(ew2 + n * 64 + k0 + 4);
        union { short8v s; unsigned u[4]; } pk;
        pk.u[0] = pkbf(lo.x, lo.y); pk.u[1] = pkbf(lo.z, lo.w);
        pk.u[2] = pkbf(hi.x, hi.y); pk.u[3] = pkbf(hi.z, hi.w);
        bw2[kt][nt] = pk.s;
        lo = *(const float4*)(chw + n * 64 + k0);
        hi = *(const float4*)(chw + n * 64 + k0 + 4);
        pk.u[0] = pkbf(lo.x, lo.y); pk.u[1] = pkbf(lo.z, lo.w);
        pk.u[2] = pkbf(hi.x, hi.y); pk.u[3] = pkbf(hi.z, hi.w);
        bwc[kt][nt] = pk.s;
      }

    const float L = Lp[0], invL = 1.0f / L;
    const float ab0 = ab[0];
    const float2 hv = *(const float2*)(ha + i0 * 64 + kp);
    const float hav0 = hv.x, hav1 = hv.y;
    const float2 w1a = *(const float2*)(ew1 + kp * 130 + 128);
    const float2 w1b = *(const float2*)(ew1 + (kp + 1) * 130 + 128);
    const float wr0 = w1a.x + w1a.y, wr1 = w1b.x + w1b.y;
    const float xi0 = x[i0 * 3 + 0], xi1 = x[i0 * 3 + 1], xi2 = x[i0 * 3 + 2];

    floatx4 agg4[4];
    #pragma unroll
    for (int nt = 0; nt < 4; ++nt) agg4[nt] = (floatx4){0.f, 0.f, 0.f, 0.f};
    float dp0 = 0.f, dp1 = 0.f, dp2 = 0.f;

    __syncthreads();

    for (int jc = 0; jc < 16; ++jc) {
      // ---- build T = silu(ha + hb + radial*wr) for this wave's 16 rows ----
      #pragma unroll
      for (int it = 0; it < 8; ++it) {
        const int row = wv16 + it * 2 + rsub;
        const int j = jc * 64 + row;
        float xd0 = xi0 - xs[j * 3 + 0];
        float xd1 = xi1 - xs[j * 3 + 1];
        float xd2 = xi2 - xs[j * 3 + 2];
        float d0 = xd0 - L * floorf(fmaf(xd0, invL, 0.5f));
        float d1 = xd1 - L * floorf(fmaf(xd1, invL, 0.5f));
        float d2 = xd2 - L * floorf(fmaf(xd2, invL, 0.5f));
        float radial = d0 * d0 + d1 * d1 + d2 * d2;
        float cinv = 1.0f / (sqrtf(radial + 1e-8f) + 1.0f);
        float2 hbv = *(const float2*)(hb + j * 64 + kp);
        float plo = fmaf(radial, wr0, hav0) + hbv.x;
        float phi = fmaf(radial, wr1, hav1) + hbv.y;
        unsigned pu = pkbf(fsilu(plo), fsilu(phi));
        // 16B unit holds 8 bf16: unit = kp>>3 (0..7), pair slot = (kp>>1)&3
        int unit = (kp >> 3) ^ (row & 7);
        *(unsigned*)(Tb + row * 128 + unit * 16 + (((kp >> 1) & 3) << 2)) = pu;
        if ((lane & 31) == 0) {
          dxs[0][row] = d0 * cinv;
          dxs[1][row] = d1 * cinv;
          dxs[2][row] = d2 * cinv;
        }
      }
      // no barrier: rows are wave-private

      // ---- GEMM1 (swapped): D1^T = ew2 * T^T ; C-init = eb2 ----
      short8v tf[2];
      #pragma unroll
      for (int kt = 0; kt < 2; ++kt) {
        int unit = (kt * 4 + g) ^ (mrow & 7);
        tf[kt] = *(const short8v*)(Tb + mrow * 128 + unit * 16);
      }
      floatx4 acc[4];
      #pragma unroll
      for (int nt = 0; nt < 4; ++nt)
        acc[nt] = *(const floatx4*)&ebs[nt * 16 + (g << 2)];
      #pragma unroll
      for (int kt = 0; kt < 2; ++kt)
        #pragma unroll
        for (int nt = 0; nt < 4; ++nt)
          acc[nt] = __builtin_amdgcn_mfma_f32_16x16x32_bf16(bw2[kt][nt], tf[kt], acc[nt], 0, 0, 0);

      // ---- epilogue 1: silu, att (row-dot over n), e, agg ----
      float p = 0.f;
      #pragma unroll
      for (int nt = 0; nt < 4; ++nt) {
        floatx4 awv = *(const floatx4*)&aws[nt * 16 + (g << 2)];
        #pragma unroll
        for (int r = 0; r < 4; ++r) {
          float s = fsilu(acc[nt][r]);
          acc[nt][r] = s;
          p = fmaf(s, awv[r], p);
        }
      }
      p += __shfl_xor(p, 16); p += __shfl_xor(p, 32);
      const float att = fsig(p + ab0);

      unsigned Pq[4][2];
      #pragma unroll
      for (int nt = 0; nt < 4; ++nt) {
        float e0 = acc[nt][0] * att, e1 = acc[nt][1] * att;
        float e2 = acc[nt][2] * att, e3 = acc[nt][3] * att;
        agg4[nt][0] += e0; agg4[nt][1] += e1;
        agg4[nt][2] += e2; agg4[nt][3] += e3;
        Pq[nt][0] = pkbf(e0, e1);
        Pq[nt][1] = pkbf(e2, e3);
      }

      // ---- assemble GEMM2 B-frags (E^T) in-register via bpermute ----
      union { short8v s; int u[4]; } ef[2];
      #pragma unroll
      for (int kt2 = 0; kt2 < 2; ++kt2)
        #pragma unroll
        for (int w = 0; w < 4; ++w) {
          int sel = (w < 2) ? selA : selB;
          int v0 = __builtin_amdgcn_ds_bpermute(sel, (int)Pq[kt2 * 2][w & 1]);
          int v1 = __builtin_amdgcn_ds_bpermute(sel, (int)Pq[kt2 * 2 + 1][w & 1]);
          ef[kt2].u[w] = ghi ? v1 : v0;
        }

      // ---- GEMM2 (swapped): D2^T = chw * E^T ; C-init = chb ----
      floatx4 acc2[4];
      #pragma unroll
      for (int nt = 0; nt < 4; ++nt)
        acc2[nt] = *(const floatx4*)&chbs[nt * 16 + (g << 2)];
      #pragma unroll
      for (int kt2 = 0; kt2 < 2; ++kt2)
        #pragma unroll
        for (int nt = 0; nt < 4; ++nt)
          acc2[nt] = __builtin_amdgcn_mfma_f32_16x16x32_bf16(bwc[kt2][nt], ef[kt2].s, acc2[nt], 0, 0, 0);

      // ---- epilogue 2: silu, cww-dot, tanh, delta ----
      float q = 0.f;
      #pragma unroll
      for (int nt = 0; nt < 4; ++nt) {
        floatx4 cwv = *(const floatx4*)&cwws[nt * 16 + (g << 2)];
        #pragma unroll
        for (int r = 0; r < 4; ++r)
          q = fmaf(fsilu(acc2[nt][r]), cwv[r], q);
      }
      q += __shfl_xor(q, 16); q += __shfl_xor(q, 32);
      const float wvv = ftanh10(q);
      if (g == 0) {
        dp0 = fmaf(dxs[0][mrow], wvv, dp0);
        dp1 = fmaf(dxs[1][mrow], wvv, dp1);
        dp2 = fmaf(dxs[2][mrow], wvv, dp2);
      }
    }

    // ---- final reductions ----
    #pragma unroll
    for (int nt = 0; nt < 4; ++nt)
      #pragma unroll
      for (int r = 0; r < 4; ++r) {
        float v = agg4[nt][r];
        v += __shfl_xor(v, 1); v += __shfl_xor(v, 2);
        v += __shfl_xor(v, 4); v += __shfl_xor(v, 8);
        agg4[nt][r] = v;
      }
    if (lr == 0) {
      #pragma unroll
      for (int nt = 0; nt < 4; ++nt)
        *(floatx4*)&redagg[wave][nt * 16 + (g << 2)] = agg4[nt];
    }
    dp0 += __shfl_xor(dp0, 1); dp0 += __shfl_xor(dp0, 2); dp0 += __shfl_xor(dp0, 4); dp0 += __shfl_xor(dp0, 8);
    dp1 += __shfl_xor(dp1, 1); dp1 += __shfl_xor(dp1, 2); dp1 += __shfl_xor(dp1, 4); dp1 += __shfl_xor(dp1, 8);
    dp2 += __shfl_xor(dp2, 1); dp2 += __shfl_xor(dp2, 2); dp2 += __shfl_xor(dp2, 4); dp2 += __shfl_xor(dp2, 8);
    if (lane == 0) { sdel[wave][0] = dp0; sdel[wave][1] = dp1; sdel[wave][2] = dp2; }
    __syncthreads();
    if (tid < 64)
      agg[i0 * 64 + tid] = redagg[0][tid] + redagg[1][tid] + redagg[2][tid] + redagg[3][tid];
    else if (tid < 67) {
      int d = tid - 64;
      delta[i0 * 3 + d] = sdel[0][d] + sdel[1][d] + sdel[2][d] + sdel[3][d];
    }
}

// Fused node update + x_new. 256 blocks x 256 thr; block owns 4 nodes.
__global__ __launch_bounds__(256) void node_fused_kernel(
    const float* __restrict__ h, const float* __restrict__ hn1,
    const float* __restrict__ agg, const float* __restrict__ nw1,
    const float* __restrict__ nw2, const float* __restrict__ nb2,
    const float* __restrict__ x, const float* __restrict__ delta,
    const float* __restrict__ Lp, float* __restrict__ outh,
    float* __restrict__ outx)
{
    __shared__ float sps[256];
    const int b = blockIdx.x, tid = threadIdx.x;
    const int gt = b * 256 + tid;
    const int i = gt >> 6, o = gt & 63;
    const float* arow = agg + i * 64;
    const float* wrow = nw1 + o * 128 + 64;
    float acc = hn1[gt];
    #pragma unroll
    for (int k = 0; k < 64; ++k) acc = fmaf(arow[k], wrow[k], acc);
    sps[tid] = fsilu(acc);
    __syncthreads();
    const float* srow = sps + (tid & ~63);
    const float* w2row = nw2 + o * 64;
    float acc2 = h[gt] + nb2[o];
    #pragma unroll
    for (int k = 0; k < 64; ++k) acc2 = fmaf(srow[k], w2row[k], acc2);
    outh[gt] = acc2;
    if (tid < 12) {
        int ii = b * 4 + tid / 3, d = tid % 3;
        float L = Lp[0];
        float v = x[ii * 3 + d] + delta[ii * 3 + d];
        outx[ii * 3 + d] = v - L * floorf(v / L);
    }
}

extern "C" void kernel_launch(void* const* d_in, const int* in_sizes, int n_in,
                              void* d_out, int out_size, void* d_ws, size_t ws_size,
                              hipStream_t stream) {
    const float* h   = (const float*)d_in[0];
    const float* x   = (const float*)d_in[1];
    const float* Lp  = (const float*)d_in[2];
    const float* ew1 = (const float*)d_in[3];
    const float* eb1 = (const float*)d_in[4];
    const float* ew2 = (const float*)d_in[5];
    const float* eb2 = (const float*)d_in[6];
    const float* nw1 = (const float*)d_in[7];
    const float* nb1 = (const float*)d_in[8];
    const float* nw2 = (const float*)d_in[9];
    const float* nb2 = (const float*)d_in[10];
    const float* chw = (const float*)d_in[11];
    const float* chb = (const float*)d_in[12];
    const float* cww = (const float*)d_in[13];
    const float* aw  = (const float*)d_in[14];
    const float* ab  = (const float*)d_in[15];

    float* ws    = (float*)d_ws;
    float* ha    = ws;             // 65536
    float* hb    = ws + 65536;     // 65536
    float* hn1   = ws + 131072;    // 65536
    float* agg   = ws + 196608;    // 65536
    float* delta = ws + 262144;    // 3072

    float* outh = (float*)d_out;       // 65536
    float* outx = outh + 65536;        // 3072

    precompute_kernel<<<768, 256, 0, stream>>>(h, ew1, eb1, nw1, nb1, ha, hb, hn1);
    edge_mfma_kernel<<<1024, 256, 0, stream>>>(x, Lp, ha, hb, ew1, ew2, eb2, chw, chb,
                                               aw, ab, cww, agg, delta);
    node_fused_kernel<<<256, 256, 0, stream>>>(h, hn1, agg, nw1, nw2, nb2, x, delta,
                                               Lp, outh, outx);
}

// Round 5
// 220.730 us; speedup vs baseline: 1.6975x; 1.6975x over previous
//
#include <hip/hip_runtime.h>

#define Nn 1024

typedef __attribute__((ext_vector_type(8))) short short8v;
typedef __attribute__((ext_vector_type(4))) float floatx4;

__device__ __forceinline__ float fsilu(float v) { return v / (1.0f + __expf(-v)); }
__device__ __forceinline__ float fsig(float v)  { return 1.0f / (1.0f + __expf(-v)); }
__device__ __forceinline__ float ftanh10(float v){ return (1.0f - 2.0f / (__expf(2.0f * v) + 1.0f)) * 10.0f; }

// pack two fp32 -> one u32 of 2 bf16 (round-half-up): 2 adds + 1 v_perm
__device__ __forceinline__ unsigned pkbf(float lo, float hi) {
    unsigned a = __float_as_uint(lo) + 0x8000u;
    unsigned b = __float_as_uint(hi) + 0x8000u;
    return __builtin_amdgcn_perm(b, a, 0x07060302u);  // {b.hi16, a.hi16}
}

// Kernel A: ha = h@Wa^T + eb1 ; hb = h@Wb^T ; hn1 = h@nw1[:, :64]^T + nb1
__global__ __launch_bounds__(256) void precompute_kernel(
    const float* __restrict__ h, const float* __restrict__ ew1,
    const float* __restrict__ eb1, const float* __restrict__ nw1,
    const float* __restrict__ nb1, float* __restrict__ ha,
    float* __restrict__ hb, float* __restrict__ hn1)
{
    int t = blockIdx.x * 256 + threadIdx.x;
    int which = t >> 16;
    int rem = t & 65535;
    int i = rem >> 6, o = rem & 63;
    const float* hrow = h + i * 64;
    const float* wrow;
    float acc;
    if (which == 0)      { wrow = ew1 + o * 130;      acc = eb1[o]; }
    else if (which == 1) { wrow = ew1 + o * 130 + 64; acc = 0.0f;   }
    else                 { wrow = nw1 + o * 128;      acc = nb1[o]; }
    #pragma unroll
    for (int k = 0; k < 64; ++k) acc = fmaf(hrow[k], wrow[k], acc);
    if (which == 0)      ha[rem]  = acc;
    else if (which == 1) hb[rem]  = acc;
    else                 hn1[rem] = acc;
}

// Edge pipeline. 256 blocks x 512 thr (8 waves) = 1 block/CU, all co-resident
// (lock-step j progression -> hb stays L2-hot). Wave w owns node blockIdx.x*4+(w&3)
// for j-half (w>>2): fully wave-private chunk loop, NO barriers inside.
// Both GEMMs computed swapped: D^T = W * T^T, output col = edge row = lane&15.
// amdgpu_waves_per_eu(2,2): pin 2 waves/EU -> 256-VGPR budget, forbid the
// LDS-occupancy heuristic from spilling regs to scratch (R4's 365MB disaster).
__global__ __launch_bounds__(512) __attribute__((amdgpu_waves_per_eu(2, 2)))
void edge_mfma_kernel(
    const float* __restrict__ x, const float* __restrict__ Lp,
    const float* __restrict__ ha, const float* __restrict__ hb,
    const float* __restrict__ ew1, const float* __restrict__ ew2,
    const float* __restrict__ eb2, const float* __restrict__ chw,
    const float* __restrict__ chb, const float* __restrict__ aw,
    const float* __restrict__ ab, const float* __restrict__ cww,
    float* __restrict__ agg, float* __restrict__ delta)
{
    __shared__ __align__(16) char Tb[8][16 * 128];   // per-wave 16 rows x 64 bf16, XOR-swizzled
    __shared__ __align__(16) float xs[Nn * 3];
    __shared__ float dxs[8][3][16];
    __shared__ float redagg[8][64];
    __shared__ float sdel[8][3];

    const int tid  = threadIdx.x;
    const int wave = tid >> 6, lane = tid & 63;
    const int lr = lane & 15, g = lane >> 4;
    const int i0 = blockIdx.x * 4 + (wave & 3);
    const int jbase = (wave >> 2) * 512;
    const int rsub = lane >> 5;          // build: which of 2 rows
    const int kp   = (lane & 31) * 2;    // build: k-pair base (bf16 elements)
    const int ghi  = g >> 1;
    const int selA = (lr + ((g & 1) << 5)) << 2;   // bpermute byte addr
    const int selB = selA + 64;
    char* TbW = Tb[wave];

    // stage x into LDS (float4)
    {
        const float4* xsrc = (const float4*)x;
        float4* xdst = (float4*)xs;
        xdst[tid] = xsrc[tid];
        if (tid < 256) xdst[tid + 512] = xsrc[tid + 512];
    }

    // weight fragments in registers (bf16): row n = lane&15, k 8-contig per g
    short8v bw2[2][4], bwc[2][4];
    #pragma unroll
    for (int kt = 0; kt < 2; ++kt)
      #pragma unroll
      for (int nt = 0; nt < 4; ++nt) {
        int n = nt * 16 + lr;
        int k0 = kt * 32 + g * 8;
        float4 lo = *(const float4*)(ew2 + n * 64 + k0);
        float4 hi = *(const float4*)(ew2 + n * 64 + k0 + 4);
        union { short8v s; unsigned u[4]; } pk;
        pk.u[0] = pkbf(lo.x, lo.y); pk.u[1] = pkbf(lo.z, lo.w);
        pk.u[2] = pkbf(hi.x, hi.y); pk.u[3] = pkbf(hi.z, hi.w);
        bw2[kt][nt] = pk.s;
        lo = *(const float4*)(chw + n * 64 + k0);
        hi = *(const float4*)(chw + n * 64 + k0 + 4);
        pk.u[0] = pkbf(lo.x, lo.y); pk.u[1] = pkbf(lo.z, lo.w);
        pk.u[2] = pkbf(hi.x, hi.y); pk.u[3] = pkbf(hi.z, hi.w);
        bwc[kt][nt] = pk.s;
      }

    // per-lane bias/weight vectors, in registers (n = nt*16 + g*4 + r)
    floatx4 ebr[4], awr[4], chbr[4], cwr[4];
    #pragma unroll
    for (int nt = 0; nt < 4; ++nt) {
      int n4 = nt * 16 + (g << 2);
      ebr[nt]  = *(const floatx4*)(eb2 + n4);
      awr[nt]  = *(const floatx4*)(aw  + n4);
      chbr[nt] = *(const floatx4*)(chb + n4);
      cwr[nt]  = *(const floatx4*)(cww + n4);
    }

    const float L = Lp[0], invL = 1.0f / L;
    const float ab0 = ab[0];
    const float2 hv = *(const float2*)(ha + i0 * 64 + kp);
    const float hav0 = hv.x, hav1 = hv.y;
    const float2 w1a = *(const float2*)(ew1 + kp * 130 + 128);
    const float2 w1b = *(const float2*)(ew1 + (kp + 1) * 130 + 128);
    const float wr0 = w1a.x + w1a.y, wr1 = w1b.x + w1b.y;

    floatx4 agg4[4];
    #pragma unroll
    for (int nt = 0; nt < 4; ++nt) agg4[nt] = (floatx4){0.f, 0.f, 0.f, 0.f};
    float dp0 = 0.f, dp1 = 0.f, dp2 = 0.f;

    __syncthreads();

    const float xi0 = xs[i0 * 3 + 0], xi1 = xs[i0 * 3 + 1], xi2 = xs[i0 * 3 + 2];

    for (int jc = 0; jc < 32; ++jc) {
      // ---- build T = silu(ha + hb + radial*wr) for this wave's 16 rows ----
      #pragma unroll
      for (int it = 0; it < 8; ++it) {
        const int row = it * 2 + rsub;
        const int j = jbase + jc * 16 + row;
        float xd0 = xi0 - xs[j * 3 + 0];
        float xd1 = xi1 - xs[j * 3 + 1];
        float xd2 = xi2 - xs[j * 3 + 2];
        float d0 = xd0 - L * floorf(fmaf(xd0, invL, 0.5f));
        float d1 = xd1 - L * floorf(fmaf(xd1, invL, 0.5f));
        float d2 = xd2 - L * floorf(fmaf(xd2, invL, 0.5f));
        float radial = d0 * d0 + d1 * d1 + d2 * d2;
        float cinv = 1.0f / (sqrtf(radial + 1e-8f) + 1.0f);
        float2 hbv = *(const float2*)(hb + j * 64 + kp);
        float plo = fmaf(radial, wr0, hav0) + hbv.x;
        float phi = fmaf(radial, wr1, hav1) + hbv.y;
        unsigned pu = pkbf(fsilu(plo), fsilu(phi));
        // 16B unit holds 8 bf16: unit = kp>>3 (0..7), pair slot = (kp>>1)&3
        int unit = (kp >> 3) ^ (row & 7);
        *(unsigned*)(TbW + row * 128 + unit * 16 + (((kp >> 1) & 3) << 2)) = pu;
        if ((lane & 31) == 0) {
          dxs[wave][0][row] = d0 * cinv;
          dxs[wave][1][row] = d1 * cinv;
          dxs[wave][2][row] = d2 * cinv;
        }
      }
      // no barrier: Tb slice is wave-private

      // ---- GEMM1 (swapped): D1^T = ew2 * T^T ; C-init = eb2 ----
      short8v tf[2];
      #pragma unroll
      for (int kt = 0; kt < 2; ++kt) {
        int unit = (kt * 4 + g) ^ (lr & 7);
        tf[kt] = *(const short8v*)(TbW + lr * 128 + unit * 16);
      }
      floatx4 acc[4];
      #pragma unroll
      for (int nt = 0; nt < 4; ++nt) acc[nt] = ebr[nt];
      #pragma unroll
      for (int kt = 0; kt < 2; ++kt)
        #pragma unroll
        for (int nt = 0; nt < 4; ++nt)
          acc[nt] = __builtin_amdgcn_mfma_f32_16x16x32_bf16(bw2[kt][nt], tf[kt], acc[nt], 0, 0, 0);

      // ---- epilogue 1: silu, att (row-dot over n), e, agg ----
      float p = 0.f;
      #pragma unroll
      for (int nt = 0; nt < 4; ++nt)
        #pragma unroll
        for (int r = 0; r < 4; ++r) {
          float s = fsilu(acc[nt][r]);
          acc[nt][r] = s;
          p = fmaf(s, awr[nt][r], p);
        }
      p += __shfl_xor(p, 16); p += __shfl_xor(p, 32);
      const float att = fsig(p + ab0);

      unsigned Pq[4][2];
      #pragma unroll
      for (int nt = 0; nt < 4; ++nt) {
        float e0 = acc[nt][0] * att, e1 = acc[nt][1] * att;
        float e2 = acc[nt][2] * att, e3 = acc[nt][3] * att;
        agg4[nt][0] += e0; agg4[nt][1] += e1;
        agg4[nt][2] += e2; agg4[nt][3] += e3;
        Pq[nt][0] = pkbf(e0, e1);
        Pq[nt][1] = pkbf(e2, e3);
      }

      // ---- assemble GEMM2 B-frags (E^T) in-register via bpermute ----
      union { short8v s; int u[4]; } ef[2];
      #pragma unroll
      for (int kt2 = 0; kt2 < 2; ++kt2)
        #pragma unroll
        for (int w = 0; w < 4; ++w) {
          int sel = (w < 2) ? selA : selB;
          int v0 = __builtin_amdgcn_ds_bpermute(sel, (int)Pq[kt2 * 2][w & 1]);
          int v1 = __builtin_amdgcn_ds_bpermute(sel, (int)Pq[kt2 * 2 + 1][w & 1]);
          ef[kt2].u[w] = ghi ? v1 : v0;
        }

      // ---- GEMM2 (swapped): D2^T = chw * E^T ; C-init = chb ----
      floatx4 acc2[4];
      #pragma unroll
      for (int nt = 0; nt < 4; ++nt) acc2[nt] = chbr[nt];
      #pragma unroll
      for (int kt2 = 0; kt2 < 2; ++kt2)
        #pragma unroll
        for (int nt = 0; nt < 4; ++nt)
          acc2[nt] = __builtin_amdgcn_mfma_f32_16x16x32_bf16(bwc[kt2][nt], ef[kt2].s, acc2[nt], 0, 0, 0);

      // ---- epilogue 2: silu, cww-dot, tanh, delta ----
      float q = 0.f;
      #pragma unroll
      for (int nt = 0; nt < 4; ++nt)
        #pragma unroll
        for (int r = 0; r < 4; ++r)
          q = fmaf(fsilu(acc2[nt][r]), cwr[nt][r], q);
      q += __shfl_xor(q, 16); q += __shfl_xor(q, 32);
      const float wvv = ftanh10(q);
      if (g == 0) {
        dp0 = fmaf(dxs[wave][0][lr], wvv, dp0);
        dp1 = fmaf(dxs[wave][1][lr], wvv, dp1);
        dp2 = fmaf(dxs[wave][2][lr], wvv, dp2);
      }
    }

    // ---- final reductions: reduce over edge rows (lr) within wave ----
    #pragma unroll
    for (int nt = 0; nt < 4; ++nt)
      #pragma unroll
      for (int r = 0; r < 4; ++r) {
        float v = agg4[nt][r];
        v += __shfl_xor(v, 1); v += __shfl_xor(v, 2);
        v += __shfl_xor(v, 4); v += __shfl_xor(v, 8);
        agg4[nt][r] = v;
      }
    if (lr == 0) {
      #pragma unroll
      for (int nt = 0; nt < 4; ++nt)
        *(floatx4*)&redagg[wave][nt * 16 + (g << 2)] = agg4[nt];
    }
    dp0 += __shfl_xor(dp0, 1); dp0 += __shfl_xor(dp0, 2); dp0 += __shfl_xor(dp0, 4); dp0 += __shfl_xor(dp0, 8);
    dp1 += __shfl_xor(dp1, 1); dp1 += __shfl_xor(dp1, 2); dp1 += __shfl_xor(dp1, 4); dp1 += __shfl_xor(dp1, 8);
    dp2 += __shfl_xor(dp2, 1); dp2 += __shfl_xor(dp2, 2); dp2 += __shfl_xor(dp2, 4); dp2 += __shfl_xor(dp2, 8);
    if (lane == 0) { sdel[wave][0] = dp0; sdel[wave][1] = dp1; sdel[wave][2] = dp2; }
    __syncthreads();
    if (tid < 256) {
      int a = tid >> 6, n = tid & 63;
      agg[(blockIdx.x * 4 + a) * 64 + n] = redagg[a][n] + redagg[a + 4][n];
    }
    if (tid < 12) {
      int a = tid / 3, d = tid % 3;
      delta[(blockIdx.x * 4 + a) * 3 + d] = sdel[a][d] + sdel[a + 4][d];
    }
}

// Fused node update + x_new. 256 blocks x 256 thr; block owns 4 nodes.
__global__ __launch_bounds__(256) void node_fused_kernel(
    const float* __restrict__ h, const float* __restrict__ hn1,
    const float* __restrict__ agg, const float* __restrict__ nw1,
    const float* __restrict__ nw2, const float* __restrict__ nb2,
    const float* __restrict__ x, const float* __restrict__ delta,
    const float* __restrict__ Lp, float* __restrict__ outh,
    float* __restrict__ outx)
{
    __shared__ float sps[256];
    const int b = blockIdx.x, tid = threadIdx.x;
    const int gt = b * 256 + tid;
    const int i = gt >> 6, o = gt & 63;
    const float* arow = agg + i * 64;
    const float* wrow = nw1 + o * 128 + 64;
    float acc = hn1[gt];
    #pragma unroll
    for (int k = 0; k < 64; ++k) acc = fmaf(arow[k], wrow[k], acc);
    sps[tid] = fsilu(acc);
    __syncthreads();
    const float* srow = sps + (tid & ~63);
    const float* w2row = nw2 + o * 64;
    float acc2 = h[gt] + nb2[o];
    #pragma unroll
    for (int k = 0; k < 64; ++k) acc2 = fmaf(srow[k], w2row[k], acc2);
    outh[gt] = acc2;
    if (tid < 12) {
        int ii = b * 4 + tid / 3, d = tid % 3;
        float L = Lp[0];
        float v = x[ii * 3 + d] + delta[ii * 3 + d];
        outx[ii * 3 + d] = v - L * floorf(v / L);
    }
}

extern "C" void kernel_launch(void* const* d_in, const int* in_sizes, int n_in,
                              void* d_out, int out_size, void* d_ws, size_t ws_size,
                              hipStream_t stream) {
    const float* h   = (const float*)d_in[0];
    const float* x   = (const float*)d_in[1];
    const float* Lp  = (const float*)d_in[2];
    const float* ew1 = (const float*)d_in[3];
    const float* eb1 = (const float*)d_in[4];
    const float* ew2 = (const float*)d_in[5];
    const float* eb2 = (const float*)d_in[6];
    const float* nw1 = (const float*)d_in[7];
    const float* nb1 = (const float*)d_in[8];
    const float* nw2 = (const float*)d_in[9];
    const float* nb2 = (const float*)d_in[10];
    const float* chw = (const float*)d_in[11];
    const float* chb = (const float*)d_in[12];
    const float* cww = (const float*)d_in[13];
    const float* aw  = (const float*)d_in[14];
    const float* ab  = (const float*)d_in[15];

    float* ws    = (float*)d_ws;
    float* ha    = ws;             // 65536
    float* hb    = ws + 65536;     // 65536
    float* hn1   = ws + 131072;    // 65536
    float* agg   = ws + 196608;    // 65536
    float* delta = ws + 262144;    // 3072

    float* outh = (float*)d_out;       // 65536
    float* outx = outh + 65536;        // 3072

    precompute_kernel<<<768, 256, 0, stream>>>(h, ew1, eb1, nw1, nb1, ha, hb, hn1);
    edge_mfma_kernel<<<256, 512, 0, stream>>>(x, Lp, ha, hb, ew1, ew2, eb2, chw, chb,
                                              aw, ab, cww, agg, delta);
    node_fused_kernel<<<256, 256, 0, stream>>>(h, hn1, agg, nw1, nw2, nb2, x, delta,
                                               Lp, outh, outx);
}